// Round 11
// baseline (162.716 us; speedup 1.0000x reference)
//
#include <hip/hip_runtime.h>

#define BLOCK 256
#define NB    2048          // 8 blocks/CU resident
#define CHUNK 1024

// Native clang vector types (nontemporal builtin rejects HIP_vector_type).
typedef float fx4 __attribute__((ext_vector_type(4)));
typedef int   ix4 __attribute__((ext_vector_type(4)));

// Branch-free BCE matching jnp: -(t*clip(log p,-100) + (1-t)*clip(log1p(-p),-100))
__device__ __forceinline__ float bce_elem(float p, float t) {
    float lp  = fmaxf(__logf(p), -100.0f);
    float l1p = fmaxf(__logf(1.0f - p), -100.0f);
    return -__builtin_fmaf(t, lp - l1p, l1p);
}

// Wave-cooperative lower_bound: first i in [0,n) with a[i] >= v (a ascending).
__device__ __forceinline__ int wave_lower_bound(const int* __restrict__ a, int n, int v) {
    const int lane = threadIdx.x & 63;
    int lo = 0, hi = n;
    while (hi - lo > 64) {
        int range  = hi - lo;
        int stride = range / 65 + 1;
        int idx    = lo + (lane + 1) * stride;
        bool lt    = (idx < hi) && (a[idx] < v);
        int  c     = __popcll(__ballot(lt));
        int  nlo   = lo + c * stride;
        int  nhi   = nlo + stride;
        if (nhi > hi) nhi = hi;
        lo = nlo; hi = nhi;
    }
    int idx = lo + lane;
    bool ge = (idx >= hi) || (a[idx] >= v);
    unsigned long long bal = __ballot(ge);
    return bal ? (lo + __ffsll(bal) - 1) : hi;
}

// Kernel 1: seg_start[s] for s=0..Bseg (st[Bseg]=n falls out naturally since
// all batch values < Bseg). One wave per boundary, 2049 waves.
__global__ __launch_bounds__(256) void bounds_kernel(
    const int* __restrict__ batch, int* __restrict__ st, int n, int Bseg)
{
    const int W = blockIdx.x * 4 + (threadIdx.x >> 6);
    if (W <= Bseg) {
        int r = wave_lower_bound(batch, n, W);
        if ((threadIdx.x & 63) == 0) st[W] = r;
    }
}

// Table walk: segment of element e. Linear-estimate guess (boundaries deviate
// from uniform by <1 segment for this data) + walk; table is 8KB, L1-hot.
__device__ __forceinline__ int seg_of_tab(const int* __restrict__ st,
                                          int Bseg, int n, int e) {
    int s = (int)(((long long)e * (long long)Bseg) / (long long)n);
    if (s > Bseg - 1) s = Bseg - 1;
    while (st[s] > e) --s;            // st[0]=0 <= e: terminates
    while (st[s + 1] <= e) ++s;       // st[Bseg]=n > e: terminates
    return s;
}

// Kernel 2: coherent-front sweep, ZERO batch bytes in the hot loop.
// r9 measured the chip-coherent chunk front at 2.93 TB/s demand-read vs 2.4
// for block-per-segment (r5) -- but spent the gain streaming batch (+32MB).
// Here routing is a pure index compare against the chunk's boundary position
// from the seg_start table (thread-0 walk, broadcast via LDS). Each chunk
// spans <=2 segments for this data (min seg ~3650 >> 1024); a middle-segment
// chunk (impossible here, but kept correct for arbitrary input) falls back to
// per-element table walk + global-atomic bins. Two sorted (seg,bce,cnt)
// entries per chunk, non-atomic. NO fences (r3: 8-XCD fence storm, 5x).
__global__ __launch_bounds__(BLOCK, 8) void stream_kernel(
    const float* __restrict__ pred, const float* __restrict__ tgt,
    const int* __restrict__ mask, const int* __restrict__ st,
    int* __restrict__ eseg, float* __restrict__ eb, float* __restrict__ ec,
    float* __restrict__ gb, float* __restrict__ gc,
    int n, int Bseg, int nchunks)
{
    const int tid = threadIdx.x;
    const int wid = tid >> 6;

    __shared__ int   sh_s0, sh_sL, sh_bnd, sh_simple;
    __shared__ float red[BLOCK / 64][4];

    for (int c = blockIdx.x; c < nchunks; c += NB) {
        const int base = c << 10;
        const int last = min(base + CHUNK - 1, n - 1);

        if (tid == 0) {
            const int s0 = seg_of_tab(st, Bseg, n, base);
            const int sL = seg_of_tab(st, Bseg, n, last);
            sh_s0  = s0;
            sh_sL  = sL;
            sh_bnd = st[sL];                       // first element of sL
            sh_simple = (st[s0 + 1] >= st[sL]) ? 1 : 0;  // no middle segment
        }
        __syncthreads();
        const int s0 = sh_s0, sL = sh_sL, bnd = sh_bnd, simple = sh_simple;

        float a0b = 0.f, a0c = 0.f, a1b = 0.f, a1c = 0.f;
        const int e0 = base + (tid << 2);

        if (simple) {
            if (e0 + 3 < n) {                      // full float4 (all but last chunk)
                fx4 p = __builtin_nontemporal_load(
                            reinterpret_cast<const fx4*>(pred) + (e0 >> 2));
                fx4 t = __builtin_nontemporal_load(
                            reinterpret_cast<const fx4*>(tgt)  + (e0 >> 2));
                ix4 m = __builtin_nontemporal_load(
                            reinterpret_cast<const ix4*>(mask) + (e0 >> 2));
                #pragma unroll
                for (int j = 0; j < 4; ++j) {
                    float mf = (float)m[j];
                    float v  = bce_elem(p[j] * mf, t[j]);
                    if (e0 + j < bnd) { a0b += v; a0c += mf; }   // pure index compare
                    else              { a1b += v; a1c += mf; }
                }
            } else if (e0 < n) {                   // ragged array tail
                for (int j = 0; j < 4 && e0 + j < n; ++j) {
                    const int e  = e0 + j;
                    float mf = (float)mask[e];
                    float v  = bce_elem(pred[e] * mf, tgt[e]);
                    if (e < bnd) { a0b += v; a0c += mf; }
                    else         { a1b += v; a1c += mf; }
                }
            }
        } else {                                   // pathological chunk: stay correct
            for (int j = 0; j < 4; ++j) {
                const int e = e0 + j;
                if (e < n) {
                    float mf = (float)mask[e];
                    float v  = bce_elem(pred[e] * mf, tgt[e]);
                    const int s = seg_of_tab(st, Bseg, n, e);
                    atomicAdd(&gb[s], v);
                    atomicAdd(&gc[s], mf);
                }
            }
        }

        // block-reduce both pairs: wave shfl -> LDS -> thread 0
        #pragma unroll
        for (int o = 32; o > 0; o >>= 1) {
            a0b += __shfl_xor(a0b, o);  a0c += __shfl_xor(a0c, o);
            a1b += __shfl_xor(a1b, o);  a1c += __shfl_xor(a1c, o);
        }
        if ((tid & 63) == 0) {
            red[wid][0] = a0b;  red[wid][1] = a0c;
            red[wid][2] = a1b;  red[wid][3] = a1c;
        }
        __syncthreads();
        if (tid == 0) {
            float sb0 = 0, sc0 = 0, sb1 = 0, sc1 = 0;
            #pragma unroll
            for (int w = 0; w < BLOCK / 64; ++w) {
                sb0 += red[w][0];  sc0 += red[w][1];
                sb1 += red[w][2];  sc1 += red[w][3];
            }
            eseg[2 * c]     = s0;  eb[2 * c]     = sb0;  ec[2 * c]     = sc0;
            eseg[2 * c + 1] = sL;  eb[2 * c + 1] = sb1;  ec[2 * c + 1] = sc1;
        }
        __syncthreads();                           // red[]/sh_* reuse safety
    }
}

// Kernel 3: one WAVE per segment (fully parallel finalize; r9's 1-block serial
// scan cost ~25us). Segment s's contributions live only in entries of chunks
// [st[s]>>10, (st[s+1]-1)>>10] -- ~10 slots, lane-parallel scan. Each block
// folds its 4 segments' per-graph values and issues ONE atomicAdd to out
// (512 single-address atomics total: negligible; r7's pathology was 320K).
__global__ __launch_bounds__(256) void pergraph_kernel(
    const int* __restrict__ st, const int* __restrict__ eseg,
    const float* __restrict__ eb, const float* __restrict__ ec,
    const float* __restrict__ gb, const float* __restrict__ gc,
    const float* __restrict__ sat_pred, const float* __restrict__ sat_tgt,
    float* __restrict__ out, int Bseg)
{
    const int tid  = threadIdx.x;
    const int wid  = tid >> 6;
    const int lane = tid & 63;
    const int S    = blockIdx.x * 4 + wid;

    float pg = 0.f;
    if (S < Bseg) {
        float sb = 0.f, sc = 0.f;
        const int ss = st[S], se = st[S + 1];
        if (ss < se) {                             // non-empty segment
            const int ilo = 2 * (ss >> 10);
            const int ihi = 2 * ((se - 1) >> 10) + 1;
            for (int i = ilo + lane; i <= ihi; i += 64) {
                if (eseg[i] == S) { sb += eb[i]; sc += ec[i]; }
            }
        }
        if (lane == 0) { sb += gb[S]; sc += gc[S]; }   // rare-fallback bins
        #pragma unroll
        for (int o = 32; o > 0; o >>= 1) {
            sb += __shfl_xor(sb, o);  sc += __shfl_xor(sc, o);
        }
        if (lane == 0) {
            pg = (sc > 0.f) ? sb / fmaxf(sc, 1.f) : 0.f;
            pg += bce_elem(sat_pred[S], sat_tgt[S]) * ((1.0f / 50.0f) / (float)Bseg);
        }
    }
    __shared__ float ws[4];
    if (lane == 0) ws[wid] = pg;
    __syncthreads();
    if (tid == 0) atomicAdd(out, (ws[0] + ws[1]) + (ws[2] + ws[3]));
}

extern "C" void kernel_launch(void* const* d_in, const int* in_sizes, int n_in,
                              void* d_out, int out_size, void* d_ws, size_t ws_size,
                              hipStream_t stream) {
    const float* y_mus_pred = (const float*)d_in[0];
    const float* y_mus      = (const float*)d_in[1];
    const float* y_sat_pred = (const float*)d_in[2];
    const float* y_sat      = (const float*)d_in[3];
    const int*   batch      = (const int*)d_in[4];
    const int*   mask       = (const int*)d_in[5];

    const int n    = in_sizes[0];
    const int Bseg = in_sizes[2];

    const int nchunks = (n + CHUNK - 1) / CHUNK;       // 7813 for N=8M

    // workspace (~212 KB): table + entry arrays + rare-fallback bins
    int*   st   = (int*)d_ws;                          // Bseg+1
    int*   eseg = st + (Bseg + 1);                     // 2*nchunks
    float* eb   = (float*)(eseg + 2 * nchunks);        // 2*nchunks
    float* ec   = eb + 2 * nchunks;                    // 2*nchunks
    float* gb   = ec + 2 * nchunks;                    // Bseg
    float* gc   = gb + Bseg;                           // Bseg

    hipMemsetAsync(gb, 0, 2 * Bseg * sizeof(float), stream);   // fallback bins
    hipMemsetAsync(d_out, 0, sizeof(float), stream);           // atomic target

    bounds_kernel<<<(Bseg + 4) / 4, 256, 0, stream>>>(batch, st, n, Bseg);
    stream_kernel<<<NB, BLOCK, 0, stream>>>(
        y_mus_pred, y_mus, mask, st, eseg, eb, ec, gb, gc, n, Bseg, nchunks);
    pergraph_kernel<<<(Bseg + 3) / 4, 256, 0, stream>>>(
        st, eseg, eb, ec, gb, gc, y_sat_pred, y_sat, (float*)d_out, Bseg);
}

// Round 12
// 154.793 us; speedup vs baseline: 1.0512x; 1.0512x over previous
//
#include <hip/hip_runtime.h>

#define BLOCK 256
#define NB    2048          // 8 blocks/CU resident
#define CHUNK 1024

// Native clang vector types (nontemporal builtin rejects HIP_vector_type).
typedef float fx4 __attribute__((ext_vector_type(4)));
typedef int   ix4 __attribute__((ext_vector_type(4)));

// Branch-free BCE matching jnp: -(t*clip(log p,-100) + (1-t)*clip(log1p(-p),-100))
__device__ __forceinline__ float bce_elem(float p, float t) {
    float lp  = fmaxf(__logf(p), -100.0f);
    float l1p = fmaxf(__logf(1.0f - p), -100.0f);
    return -__builtin_fmaf(t, lp - l1p, l1p);
}

// Wave-cooperative lower_bound: first i in [0,n) with a[i] >= v (a ascending).
__device__ __forceinline__ int wave_lower_bound(const int* __restrict__ a, int n, int v) {
    const int lane = threadIdx.x & 63;
    int lo = 0, hi = n;
    while (hi - lo > 64) {
        int range  = hi - lo;
        int stride = range / 65 + 1;
        int idx    = lo + (lane + 1) * stride;
        bool lt    = (idx < hi) && (a[idx] < v);
        int  c     = __popcll(__ballot(lt));
        int  nlo   = lo + c * stride;
        int  nhi   = nlo + stride;
        if (nhi > hi) nhi = hi;
        lo = nlo; hi = nhi;
    }
    int idx = lo + lane;
    bool ge = (idx >= hi) || (a[idx] >= v);
    unsigned long long bal = __ballot(ge);
    return bal ? (lo + __ffsll(bal) - 1) : hi;
}

// Lean coherent-front sweep (r11 hot loop, scaffolding stripped).
// r11 evidence: stream dropped below 40us but 3 extra dispatches + bounds
// kernel (+12us) ate the gain. Here each chunk self-resolves routing:
// 2 scalar batch loads; boundary chunks (~26%) add a ~10-step thread-0
// binary search whose latency hides under the bulk nt-loads issued first.
// Batch bytes ~2MB total (vs 32MB streamed in r9). Each chunk spans <=2
// segments for this data (min seg ~3650 >> 1024); middle-segment chunks
// (never here) take a serial-correct path folding whole middle segments
// into out via one atomic. NO fences (r3: 8-XCD fence storm, 5x).
__global__ __launch_bounds__(BLOCK, 8) void stream_kernel(
    const float* __restrict__ pred, const float* __restrict__ tgt,
    const int* __restrict__ batch, const int* __restrict__ mask,
    int* __restrict__ eseg, float* __restrict__ eb, float* __restrict__ ec,
    float* __restrict__ out, int n, int nchunks)
{
    const int tid = threadIdx.x;
    const int wid = tid >> 6;

    __shared__ int   sh_s0, sh_sL, sh_bnd, sh_simple;
    __shared__ float red[BLOCK / 64][4];

    for (int c = blockIdx.x; c < nchunks; c += NB) {
        const int base = c << 10;
        const int last = min(base + CHUNK - 1, n - 1);
        const int e0   = base + (tid << 2);
        const bool full = (e0 + 3 < n);

        // bulk loads FIRST: boundary resolution below overlaps their latency
        fx4 p = {0.f, 0.f, 0.f, 0.f};
        fx4 t = {0.f, 0.f, 0.f, 0.f};
        ix4 m = {0, 0, 0, 0};
        if (full) {
            p = __builtin_nontemporal_load(
                    reinterpret_cast<const fx4*>(pred) + (e0 >> 2));
            t = __builtin_nontemporal_load(
                    reinterpret_cast<const fx4*>(tgt)  + (e0 >> 2));
            m = __builtin_nontemporal_load(
                    reinterpret_cast<const ix4*>(mask) + (e0 >> 2));
        }

        if (tid == 0) {
            const int s0 = batch[base];
            const int sL = batch[last];
            int bnd = base;                    // sL==s0: everything -> a1 (seg s0 too)
            if (sL != s0) {                    // first idx in (base,last] with batch>=sL
                int lo = base + 1, hi = last;
                while (lo < hi) {
                    int mid = (lo + hi) >> 1;
                    if (batch[mid] < sL) lo = mid + 1; else hi = mid;
                }
                bnd = lo;
            }
            sh_s0 = s0;  sh_sL = sL;  sh_bnd = bnd;
            sh_simple = (sL <= s0 + 1) ? 1 : 0;
        }
        __syncthreads();
        const int s0 = sh_s0, sL = sh_sL, bnd = sh_bnd, simple = sh_simple;

        float a0b = 0.f, a0c = 0.f, a1b = 0.f, a1c = 0.f;
        if (simple) {
            if (full) {
                #pragma unroll
                for (int j = 0; j < 4; ++j) {
                    float mf = (float)m[j];
                    float v  = bce_elem(p[j] * mf, t[j]);
                    if (e0 + j < bnd) { a0b += v; a0c += mf; }   // index compare only
                    else              { a1b += v; a1c += mf; }
                }
            } else if (e0 < n) {               // ragged array tail
                for (int j = 0; j < 4 && e0 + j < n; ++j) {
                    const int e  = e0 + j;
                    float mf = (float)mask[e];
                    float v  = bce_elem(pred[e] * mf, tgt[e]);
                    if (e < bnd) { a0b += v; a0c += mf; }
                    else         { a1b += v; a1c += mf; }
                }
            }
        }

        // block-reduce both pairs: wave shfl -> LDS -> thread 0
        #pragma unroll
        for (int o = 32; o > 0; o >>= 1) {
            a0b += __shfl_xor(a0b, o);  a0c += __shfl_xor(a0c, o);
            a1b += __shfl_xor(a1b, o);  a1c += __shfl_xor(a1c, o);
        }
        if ((tid & 63) == 0) {
            red[wid][0] = a0b;  red[wid][1] = a0c;
            red[wid][2] = a1b;  red[wid][3] = a1c;
        }
        __syncthreads();
        if (tid == 0) {
            if (simple) {
                float sb0 = 0, sc0 = 0, sb1 = 0, sc1 = 0;
                #pragma unroll
                for (int w = 0; w < BLOCK / 64; ++w) {
                    sb0 += red[w][0];  sc0 += red[w][1];
                    sb1 += red[w][2];  sc1 += red[w][3];
                }
                eseg[2 * c]     = s0;  eb[2 * c]     = sb0;  ec[2 * c]     = sc0;
                eseg[2 * c + 1] = sL;  eb[2 * c + 1] = sb1;  ec[2 * c + 1] = sc1;
            } else {
                // pathological chunk (middle segment wholly inside): serial-correct.
                // Middle segments are complete here -> fold pg directly into out
                // (sat term added for every segment by pergraph_kernel).
                float sb0 = 0, sc0 = 0, sb1 = 0, sc1 = 0;
                float mb = 0, mc = 0;  int cur = -1;
                for (int e = base; e <= last; ++e) {
                    float mf = (float)mask[e];
                    float v  = bce_elem(pred[e] * mf, tgt[e]);
                    int   s  = batch[e];
                    if (s == s0)      { sb0 += v; sc0 += mf; }
                    else if (s == sL) { sb1 += v; sc1 += mf; }
                    else {
                        if (s != cur) {
                            if (cur >= 0 && mc > 0.f) atomicAdd(out, mb / fmaxf(mc, 1.f));
                            cur = s;  mb = 0.f;  mc = 0.f;
                        }
                        mb += v;  mc += mf;
                    }
                }
                if (cur >= 0 && mc > 0.f) atomicAdd(out, mb / fmaxf(mc, 1.f));
                eseg[2 * c]     = s0;  eb[2 * c]     = sb0;  ec[2 * c]     = sc0;
                eseg[2 * c + 1] = sL;  eb[2 * c + 1] = sb1;  ec[2 * c + 1] = sc1;
            }
        }
        __syncthreads();                       // red[]/sh_* reuse safety
    }
}

// One WAVE per segment. Entries are sorted by segment (chunk order ==
// address order == segment order); wave-searches the entry array for its
// segment (3 gather rounds on 15.6K L2-hot ints), lane-parallel window scan
// (<=12 entries/segment for this data; while-loop stays correct otherwise).
// One atomicAdd per block into out (512 total -- negligible).
__global__ __launch_bounds__(256) void pergraph_kernel(
    const int* __restrict__ eseg, const float* __restrict__ eb,
    const float* __restrict__ ec,
    const float* __restrict__ sat_pred, const float* __restrict__ sat_tgt,
    float* __restrict__ out, int nentries, int Bseg)
{
    const int tid  = threadIdx.x;
    const int wid  = tid >> 6;
    const int lane = tid & 63;
    const int S    = blockIdx.x * 4 + wid;

    float pg = 0.f;
    if (S < Bseg) {
        const int idx = wave_lower_bound(eseg, nentries, S);
        float sb = 0.f, sc = 0.f;
        for (int w = 0;; ++w) {
            const int i = idx + w * 64 + lane;
            const bool hit = (i < nentries) && (eseg[i] == S);
            if (hit) { sb += eb[i]; sc += ec[i]; }
            if (__popcll(__ballot(hit)) < 64) break;   // window not full -> done
        }
        #pragma unroll
        for (int o = 32; o > 0; o >>= 1) {
            sb += __shfl_xor(sb, o);  sc += __shfl_xor(sc, o);
        }
        if (lane == 0) {
            pg = (sc > 0.f) ? sb / fmaxf(sc, 1.f) : 0.f;
            pg += bce_elem(sat_pred[S], sat_tgt[S]) * ((1.0f / 50.0f) / (float)Bseg);
        }
    }
    __shared__ float ws[4];
    if (lane == 0) ws[wid] = pg;
    __syncthreads();
    if (tid == 0) atomicAdd(out, (ws[0] + ws[1]) + (ws[2] + ws[3]));
}

extern "C" void kernel_launch(void* const* d_in, const int* in_sizes, int n_in,
                              void* d_out, int out_size, void* d_ws, size_t ws_size,
                              hipStream_t stream) {
    const float* y_mus_pred = (const float*)d_in[0];
    const float* y_mus      = (const float*)d_in[1];
    const float* y_sat_pred = (const float*)d_in[2];
    const float* y_sat      = (const float*)d_in[3];
    const int*   batch      = (const int*)d_in[4];
    const int*   mask       = (const int*)d_in[5];

    const int n    = in_sizes[0];
    const int Bseg = in_sizes[2];

    const int nchunks  = (n + CHUNK - 1) / CHUNK;     // 7813 for N=8M
    const int nentries = 2 * nchunks;

    // workspace (~188 KB): sorted (seg,bce,cnt) entry arrays only
    int*   eseg = (int*)d_ws;
    float* eb   = (float*)(eseg + nentries);
    float* ec   = eb + nentries;

    hipMemsetAsync(d_out, 0, sizeof(float), stream);  // atomic target (4 B)
    stream_kernel<<<NB, BLOCK, 0, stream>>>(
        y_mus_pred, y_mus, batch, mask, eseg, eb, ec, (float*)d_out, n, nchunks);
    pergraph_kernel<<<(Bseg + 3) / 4, 256, 0, stream>>>(
        eseg, eb, ec, y_sat_pred, y_sat, (float*)d_out, nentries, Bseg);
}

// Round 13
// 149.764 us; speedup vs baseline: 1.0865x; 1.0336x over previous
//
#include <hip/hip_runtime.h>

#define BLOCK 256

// Native clang vector types (nontemporal builtin rejects HIP_vector_type).
typedef float fx4 __attribute__((ext_vector_type(4)));
typedef int   ix4 __attribute__((ext_vector_type(4)));

// Branch-free BCE matching jnp: -(t*clip(log p,-100) + (1-t)*clip(log1p(-p),-100))
__device__ __forceinline__ float bce_elem(float p, float t) {
    float lp  = fmaxf(__logf(p), -100.0f);
    float l1p = fmaxf(__logf(1.0f - p), -100.0f);
    return -__builtin_fmaf(t, lp - l1p, l1p);
}

// Wave-cooperative lower_bound: first i in [0,n) with a[i] >= v (a ascending).
__device__ __forceinline__ int wave_lower_bound(const int* __restrict__ a, int n, int v) {
    const int lane = threadIdx.x & 63;
    int lo = 0, hi = n;
    while (hi - lo > 64) {
        int range  = hi - lo;
        int stride = range / 65 + 1;
        int idx    = lo + (lane + 1) * stride;
        bool lt    = (idx < hi) && (a[idx] < v);
        int  c     = __popcll(__ballot(lt));
        int  nlo   = lo + c * stride;
        int  nhi   = nlo + stride;
        if (nhi > hi) nhi = hi;
        lo = nlo; hi = nhi;
    }
    int idx = lo + lane;
    bool ge = (idx >= hi) || (a[idx] >= v);
    unsigned long long bal = __ballot(ge);
    return bal ? (lo + __ffsll(bal) - 1) : hi;
}

#define PROC(p, t, m)                                                          \
    do {                                                                       \
        float m0 = (float)(m)[0], m1 = (float)(m)[1],                          \
              m2 = (float)(m)[2], m3 = (float)(m)[3];                          \
        accb += bce_elem((p)[0] * m0, (t)[0]);  accc += m0;                    \
        accb += bce_elem((p)[1] * m1, (t)[1]);  accc += m1;                    \
        accb += bce_elem((p)[2] * m2, (t)[2]);  accc += m2;                    \
        accb += bce_elem((p)[3] * m3, (t)[3]);  accc += m3;                    \
    } while (0)

// FINAL (r13 = r10 restore, best measured total 151.23us). Session ledger:
// concurrency (r1/r2/r8: unroll, sched_barrier pipeline, DMA+counted vmcnt),
// search depth (r1), writeback (r5 nt / r8), fused-sum fences (r3: 5x regr),
// atomics (r7: 100us warm), front shape (r9/r11/r12: +26% byte-rate, eaten
// by scaffolding), XCD locality (r10) -- all null or negative. Duration is
// invariant to HBM-vs-L3 serving (r8/r9 warm replays); the wall is the chip
// read-serve path at ~2.4-2.9 TB/s vs 3.15 copy-read-half. 96 MB demand is
// irreducible => ~33-40us kernel floor; rest of dur_us is fixed harness cost.
__global__ __launch_bounds__(BLOCK, 8) void seg_kernel(
    const float* __restrict__ pred, const float* __restrict__ tgt,
    const int* __restrict__ batch, const int* __restrict__ mask,
    const float* __restrict__ sat_pred, const float* __restrict__ sat_tgt,
    float* __restrict__ per_graph, int n, int Bseg)
{
    const int bid = blockIdx.x;
    // XCD-contiguous segment assignment (Bseg=2048=8*256 exactly; identity
    // fallback keeps generality if Bseg isn't a multiple of 8).
    const int b = ((Bseg & 7) == 0) ? ((bid & 7) * (Bseg >> 3) + (bid >> 3))
                                    : bid;
    const int tid = threadIdx.x;

    __shared__ int sh_bounds[2];
    const int wid = tid >> 6;
    if (wid < 2) {                            // wave 0 -> lo, wave 1 -> hi, concurrent
        int r = wave_lower_bound(batch, n, b + wid);
        if ((tid & 63) == 0) sh_bounds[wid] = r;
    }
    __syncthreads();
    const int lo = sh_bounds[0], hi = sh_bounds[1];   // block owns batch range [lo,hi)

    float accb = 0.0f, accc = 0.0f;

    int a0 = (lo + 3) & ~3;                   // first 16B-aligned element
    if (a0 > hi) a0 = hi;
    const int nvec = (hi - a0) >> 2;
    const int a1   = a0 + (nvec << 2);

    // scalar head (<=3 elems)
    for (int i = lo + tid; i < a0; i += BLOCK) {
        float mf = (float)mask[i];
        accb += bce_elem(pred[i] * mf, tgt[i]);
        accc += mf;
    }

    // vector body: 3 coalesced 16B streams, 3x unroll, ALL loads non-temporal.
    const fx4* p4 = reinterpret_cast<const fx4*>(pred) + (a0 >> 2);
    const fx4* t4 = reinterpret_cast<const fx4*>(tgt)  + (a0 >> 2);
    const ix4* m4 = reinterpret_cast<const ix4*>(mask) + (a0 >> 2);

    int i = tid;
    const int nv2 = nvec - 2 * BLOCK;
    for (; i < nv2; i += 3 * BLOCK) {
        fx4 pa = __builtin_nontemporal_load(p4 + i);
        fx4 pb = __builtin_nontemporal_load(p4 + i + BLOCK);
        fx4 pc = __builtin_nontemporal_load(p4 + i + 2 * BLOCK);
        fx4 ta = __builtin_nontemporal_load(t4 + i);
        fx4 tb = __builtin_nontemporal_load(t4 + i + BLOCK);
        fx4 tc = __builtin_nontemporal_load(t4 + i + 2 * BLOCK);
        ix4 ma = __builtin_nontemporal_load(m4 + i);
        ix4 mb = __builtin_nontemporal_load(m4 + i + BLOCK);
        ix4 mc = __builtin_nontemporal_load(m4 + i + 2 * BLOCK);
        PROC(pa, ta, ma);
        PROC(pb, tb, mb);
        PROC(pc, tc, mc);
    }
    for (; i < nvec; i += BLOCK) {            // remainder (<=2 strided iters/thread)
        fx4 p = __builtin_nontemporal_load(p4 + i);
        fx4 t = __builtin_nontemporal_load(t4 + i);
        ix4 m = __builtin_nontemporal_load(m4 + i);
        PROC(p, t, m);
    }

    // scalar tail (<=3 elems)
    for (int k = a1 + tid; k < hi; k += BLOCK) {
        float mf = (float)mask[k];
        accb += bce_elem(pred[k] * mf, tgt[k]);
        accc += mf;
    }

    // block reduction: wave shfl -> LDS -> thread 0
    #pragma unroll
    for (int o = 32; o > 0; o >>= 1) {
        accb += __shfl_xor(accb, o);
        accc += __shfl_xor(accc, o);
    }
    __shared__ float wb[4], wc[4];
    if ((tid & 63) == 0) { wb[tid >> 6] = accb; wc[tid >> 6] = accc; }
    __syncthreads();
    if (tid == 0) {
        float sb = wb[0] + wb[1] + wb[2] + wb[3];
        float sc = wc[0] + wc[1] + wc[2] + wc[3];
        float pg = (sc > 0.0f) ? sb / fmaxf(sc, 1.0f) : 0.0f;
        // fold this graph's share of the sat-BCE mean*L1 term; every b covered once
        pg += bce_elem(sat_pred[b], sat_tgt[b]) * ((1.0f / 50.0f) / (float)Bseg);
        per_graph[b] = pg;                    // plain store: no atomics, no fences
    }
}

__global__ __launch_bounds__(256) void sum_kernel(
    const float* __restrict__ per_graph, float* __restrict__ out, int Bseg)
{
    float local = 0.0f;
    for (int i = threadIdx.x; i < Bseg; i += 256) local += per_graph[i];
    #pragma unroll
    for (int o = 32; o > 0; o >>= 1) local += __shfl_xor(local, o);
    __shared__ float ws[4];
    if ((threadIdx.x & 63) == 0) ws[threadIdx.x >> 6] = local;
    __syncthreads();
    if (threadIdx.x == 0) out[0] = ws[0] + ws[1] + ws[2] + ws[3];
}

extern "C" void kernel_launch(void* const* d_in, const int* in_sizes, int n_in,
                              void* d_out, int out_size, void* d_ws, size_t ws_size,
                              hipStream_t stream) {
    const float* y_mus_pred = (const float*)d_in[0];
    const float* y_mus      = (const float*)d_in[1];
    const float* y_sat_pred = (const float*)d_in[2];
    const float* y_sat      = (const float*)d_in[3];
    const int*   batch      = (const int*)d_in[4];
    const int*   mask       = (const int*)d_in[5];

    const int n    = in_sizes[0];
    const int Bseg = in_sizes[2];

    float* per_graph = (float*)d_ws;   // Bseg floats; every slot written each launch

    seg_kernel<<<Bseg, BLOCK, 0, stream>>>(
        y_mus_pred, y_mus, batch, mask, y_sat_pred, y_sat, per_graph, n, Bseg);
    sum_kernel<<<1, 256, 0, stream>>>(per_graph, (float*)d_out, Bseg);
}